// Round 17
// baseline (109.721 us; speedup 1.0000x reference)
//
#include <hip/hip_runtime.h>
#include <math.h>

#define N_EMBD    4096
#define N_EXPERTS 64
#define N_TOKENS  16384
#define TAU       1e-3f
#define NT_BLK    32                  // tokens per block
#define KS        2                   // K-split across blocks
#define K_BLK     (N_EMBD / KS)       // 2048 f32 per block
#define BK        128                 // K per LDS tile
#define NT2       (K_BLK / BK)        // 16 tiles per block
#define PLANE     8192                // hi plane: 32 rows x 256 B
#define BUFB      (2 * PLANE)         // hi+lo per buffer

typedef __attribute__((ext_vector_type(8))) short bf16x8;
typedef __attribute__((ext_vector_type(4))) float f32x4;

#define MFMA16 __builtin_amdgcn_mfma_f32_16x16x32_bf16

struct hl_pair { unsigned h, l; };

// ---------------------------------------------------------------------------
// f32 -> (bf16 hi, bf16 lo) RNE split, pair-packed into one u32 each.
// ---------------------------------------------------------------------------
__device__ __forceinline__ hl_pair split_pair(float f0, float f1) {
    unsigned u0 = __builtin_bit_cast(unsigned, f0);
    unsigned u1 = __builtin_bit_cast(unsigned, f1);
    unsigned r0 = u0 + 0x7FFFu + ((u0 >> 16) & 1u);
    unsigned r1 = u1 + 0x7FFFu + ((u1 >> 16) & 1u);
    hl_pair p;
    p.h = (r0 >> 16) | (r1 & 0xFFFF0000u);
    float h0 = __builtin_bit_cast(float, r0 & 0xFFFF0000u);
    float h1 = __builtin_bit_cast(float, r1 & 0xFFFF0000u);
    float l0 = f0 - h0;
    float l1 = f1 - h1;
    unsigned v0 = __builtin_bit_cast(unsigned, l0);
    unsigned v1 = __builtin_bit_cast(unsigned, l1);
    unsigned s0 = v0 + 0x7FFFu + ((v0 >> 16) & 1u);
    unsigned s1 = v1 + 0x7FFFu + ((v1 >> 16) & 1u);
    p.l = (s0 >> 16) | (s1 & 0xFFFF0000u);
    return p;
}

// ---------------------------------------------------------------------------
// Kernel 0: pack W into bf16 hi/lo MFMA B-fragments; zero the flag counter.
// Frag F = ks*8 + nt*2 + term. Lane l elem j = W[nt*16+(l&15)][ks*32+(l>>4)*8+j]
// ---------------------------------------------------------------------------
__global__ void w_pack_bf16(const float* __restrict__ W,
                            uint4* __restrict__ Bpack,
                            int* __restrict__ flags) {
    int tid = blockIdx.x * blockDim.x + threadIdx.x;   // 32768
    if (tid == 0) flags[0] = 0;
    int lane = tid & 63;
    int nt   = (tid >> 6) & 3;
    int ks   = tid >> 8;                               // 0..127
    int e = nt * 16 + (lane & 15);
    int k = ks * 32 + ((lane >> 4) << 3);
    const float* src = W + (size_t)e * N_EMBD + k;
    uint4 hp, lp;
    hl_pair p0 = split_pair(src[0], src[1]);
    hl_pair p1 = split_pair(src[2], src[3]);
    hl_pair p2 = split_pair(src[4], src[5]);
    hl_pair p3 = split_pair(src[6], src[7]);
    hp.x = p0.h; lp.x = p0.l;
    hp.y = p1.h; lp.y = p1.l;
    hp.z = p2.h; lp.z = p2.l;
    hp.w = p3.h; lp.w = p3.l;
    size_t F = (size_t)ks * 8 + nt * 2;
    Bpack[F * 64 + lane]       = hp;
    Bpack[(F + 1) * 64 + lane] = lp;
}

// ---------------------------------------------------------------------------
// Split 4 f32 into bf16 hi/lo (uint2 each) and write to the two planes.
// ---------------------------------------------------------------------------
__device__ __forceinline__ void store_chunk(char* buf, int off, f32x4 v) {
    hl_pair p01 = split_pair(v.x, v.y);
    hl_pair p23 = split_pair(v.z, v.w);
    uint2 hw, lw;
    hw.x = p01.h; hw.y = p23.h;
    lw.x = p01.l; lw.y = p23.l;
    *(uint2*)(buf + off)         = hw;
    *(uint2*)(buf + off + PLANE) = lw;
}

// ---------------------------------------------------------------------------
// Kernel 1: router GEMM — BK=128 mega-tiles (r16 post-mortem: time ≈
// tile-instances x per-tile fixed cost ~1.6k cy; halving tile count from
// 32768 to 16384 amortizes the barrier/drain convoy). KS=2, grid 1024 =
// exactly 4 blocks/CU x 256 (one round). Both operands register-prefetched
// a full phase ahead; ONE counted vmcnt wait per phase (at STOREA, for a
// load issued ~2.5k cy earlier); sched_barrier(0) pins issue order.
// Swizzle: physical = logical ^ ((row&7)<<4) on full offsets, both sides;
// bank math = uniform 32B/bank per access (minimum-time).
// partial layout: [KS][N_TOKENS][64] f32.
// ---------------------------------------------------------------------------
__global__ __launch_bounds__(256, 4) void router_gemm(
        const float* __restrict__ x,
        const uint4* __restrict__ Bpack,
        float* __restrict__ partial) {
    __shared__ __align__(16) char ldsA[2 * BUFB];   // 2 bufs x {hi 8KB, lo 8KB}

    const int tid  = threadIdx.x;
    const int lane = tid & 63;
    const int w    = tid >> 6;                  // wave = expert quarter
    const int kq   = blockIdx.x & 1;            // K half
    const int tok0 = (blockIdx.x >> 1) * NT_BLK;
    const int l15 = lane & 15, l16 = lane >> 4;

    // staging: thread -> row tid>>3 (0..31), f32x4 chunks {c8, c8+8, c8+16, c8+24}
    const int row_w = tid >> 3;
    const int c8    = tid & 7;
    const f32x4* g = (const f32x4*)(x + (size_t)(tok0 + row_w) * N_EMBD
                                      + kq * K_BLK) + c8;
    const int swz = (row_w & 7) << 4;
    int wo[4];
#pragma unroll
    for (int j = 0; j < 4; ++j)
        wo[j] = row_w * 256 + (((c8 + 8 * j) * 8) ^ swz);

    // fragment reads: lane -> row l15 (Mtile0) / +16 (Mtile1), 4 K-steps
    const int swz_r = (l15 & 7) << 4;
    int ro[4];
#pragma unroll
    for (int ksl = 0; ksl < 4; ++ksl)
        ro[ksl] = l15 * 256 + ((l16 * 16 + ksl * 64) ^ swz_r);

    f32x4 acc0 = {0.f, 0.f, 0.f, 0.f};
    f32x4 acc1 = {0.f, 0.f, 0.f, 0.f};
    f32x4 ra[4];                                // A f32 prefetch (1 tile)
    uint4 bah[4], bal[4], bbh[4], bbl[4];       // B regs, 2 buffers

    char* buf0 = ldsA;
    char* buf1 = ldsA + BUFB;

#define LOADA(t) { _Pragma("unroll")                                          \
    for (int j = 0; j < 4; ++j) ra[j] = g[(t) * 32 + j * 8]; }
#define STOREA(buf) { _Pragma("unroll")                                       \
    for (int j = 0; j < 4; ++j) store_chunk(buf, wo[j], ra[j]); }
#define LOADB(H, L, tt) { const uint4* _q = Bpack                             \
        + ((size_t)(kq * (K_BLK / 32) + (tt) * 4) * 8 + w * 2) * 64 + lane;   \
    _Pragma("unroll")                                                         \
    for (int ksl = 0; ksl < 4; ++ksl) {                                       \
        H[ksl] = _q[ksl * 512]; L[ksl] = _q[ksl * 512 + 64]; } }
#define COMPUTE(bufR, H, L) { _Pragma("unroll")                               \
    for (int ksl = 0; ksl < 4; ++ksl) {                                       \
        bf16x8 bh = __builtin_bit_cast(bf16x8, H[ksl]);                       \
        bf16x8 bl = __builtin_bit_cast(bf16x8, L[ksl]);                       \
        bf16x8 a;                                                             \
        a = *(const bf16x8*)((bufR) + ro[ksl]);                               \
        acc0 = MFMA16(a, bh, acc0, 0, 0, 0);                                  \
        acc0 = MFMA16(a, bl, acc0, 0, 0, 0);                                  \
        a = *(const bf16x8*)((bufR) + ro[ksl] + PLANE);                       \
        acc0 = MFMA16(a, bh, acc0, 0, 0, 0);                                  \
        a = *(const bf16x8*)((bufR) + ro[ksl] + 4096);                        \
        acc1 = MFMA16(a, bh, acc1, 0, 0, 0);                                  \
        acc1 = MFMA16(a, bl, acc1, 0, 0, 0);                                  \
        a = *(const bf16x8*)((bufR) + ro[ksl] + 4096 + PLANE);                \
        acc1 = MFMA16(a, bh, acc1, 0, 0, 0);                                  \
    } }

    // prologue: stage tile 0; issue B(0) and A(1)
    LOADA(0);
    STOREA(buf0);                               // one-time stall for A(0)
    LOADB(bah, bal, 0);
    LOADA(1);
    __builtin_amdgcn_sched_barrier(0);
    asm volatile("s_waitcnt lgkmcnt(0)" ::: "memory");
    __builtin_amdgcn_s_barrier();
    __builtin_amdgcn_sched_barrier(0);

    for (int t = 0; t < NT2; t += 2) {
        // ---- phase A: tile t on buf0 with B=ba ----
        LOADB(bbh, bbl, t + 1);                 // youngest: survives ra-wait
        __builtin_amdgcn_sched_barrier(0);
        STOREA(buf1);                           // waits ra(t+1); drains ba too
        if (t + 2 < NT2) LOADA(t + 2);
        __builtin_amdgcn_sched_barrier(0);
        COMPUTE(buf0, bah, bal);                // B resident (drained above)
        asm volatile("s_waitcnt lgkmcnt(0)" ::: "memory");
        __builtin_amdgcn_s_barrier();
        __builtin_amdgcn_sched_barrier(0);

        // ---- phase B: tile t+1 on buf1 with B=bb ----
        if (t + 2 < NT2) {
            LOADB(bah, bal, t + 2);
            __builtin_amdgcn_sched_barrier(0);
            STOREA(buf0);                       // waits ra(t+2); drains bb
            if (t + 3 < NT2) LOADA(t + 3);
            __builtin_amdgcn_sched_barrier(0);
            COMPUTE(buf1, bbh, bbl);
            asm volatile("s_waitcnt lgkmcnt(0)" ::: "memory");
            __builtin_amdgcn_s_barrier();
            __builtin_amdgcn_sched_barrier(0);
        } else {
            COMPUTE(buf1, bbh, bbl);            // final tile
        }
    }
#undef LOADA
#undef STOREA
#undef LOADB
#undef COMPUTE

    // C layout: row(token in M-tile) = l16*4 + j, col(expert in quarter) = l15
    float* po = partial + ((size_t)kq * N_TOKENS + tok0) * 64 + w * 16 + l15;
#pragma unroll
    for (int j = 0; j < 4; ++j) {
        po[(size_t)(l16 * 4 + j) * 64]      = acc0[j];
        po[(size_t)(16 + l16 * 4 + j) * 64] = acc1[j];
    }
}

// ---------------------------------------------------------------------------
// Kernel 2: finalize. Wave per token; sum 2 K-half partials; top-3
// butterflies; softmax of top-2; near-tie flagging for refine.
// ---------------------------------------------------------------------------
__global__ void finalize(const float* __restrict__ partial,
                         float* __restrict__ out,
                         int* __restrict__ flags) {
    const int lane = threadIdx.x & 63;
    const int tok  = blockIdx.x * 4 + (threadIdx.x >> 6);

    float v = partial[(size_t)tok * 64 + lane]
            + partial[((size_t)N_TOKENS + tok) * 64 + lane];

    float m1 = v; int i1 = lane;
#pragma unroll
    for (int off = 32; off; off >>= 1) {
        float ov = __shfl_xor(m1, off); int oi = __shfl_xor(i1, off);
        if (ov > m1 || (ov == m1 && oi < i1)) { m1 = ov; i1 = oi; }
    }
    float m2 = (lane == i1) ? -INFINITY : v; int i2 = lane;
#pragma unroll
    for (int off = 32; off; off >>= 1) {
        float ov = __shfl_xor(m2, off); int oi = __shfl_xor(i2, off);
        if (ov > m2 || (ov == m2 && oi < i2)) { m2 = ov; i2 = oi; }
    }
    float m3 = (lane == i1 || lane == i2) ? -INFINITY : v;
#pragma unroll
    for (int off = 32; off; off >>= 1)
        m3 = fmaxf(m3, __shfl_xor(m3, off));

    if (lane == 0) {
        float e2  = __expf(m2 - m1);
        float inv = 1.0f / (1.0f + e2);
        float2 idx = make_float2((float)i1, (float)i2);
        float2 gts = make_float2(inv, e2 * inv);
        *(float2*)(out + 2 * tok) = idx;
        *(float2*)(out + 2 * N_TOKENS + 2 * tok) = gts;
        if ((m1 - m2 < TAU) || (m2 - m3 < TAU)) {
            int p = atomicAdd(flags, 1);
            if (p < N_TOKENS) flags[1 + p] = tok;
        }
    }
}

// ---------------------------------------------------------------------------
// Kernel 3: exact f64 refinement of flagged near-tie tokens. Block per token
// (grid-strided). Wave wv handles experts wv*16..+16, lanes split K.
// ---------------------------------------------------------------------------
__global__ __launch_bounds__(256) void refine(const float* __restrict__ x,
                                              const float* __restrict__ W,
                                              const int* __restrict__ flags,
                                              float* __restrict__ out) {
    __shared__ double redd[64];
    const int lane = threadIdx.x & 63;
    const int wv   = threadIdx.x >> 6;
    int cnt = flags[0];
    if (cnt > N_TOKENS) cnt = N_TOKENS;

    for (int i = blockIdx.x; i < cnt; i += gridDim.x) {
        const int tok = flags[1 + i];
        const float4* xr4 = (const float4*)(x + (size_t)tok * N_EMBD);
#pragma unroll
        for (int ee = 0; ee < 16; ++ee) {
            const int e = wv * 16 + ee;
            const float4* wr = (const float4*)(W + (size_t)e * N_EMBD);
            double acc = 0.0;
#pragma unroll 4
            for (int c = 0; c < 16; ++c) {
                float4 xv = xr4[c * 64 + lane];
                float4 wq = wr[c * 64 + lane];
                acc += (double)xv.x * wq.x + (double)xv.y * wq.y
                     + (double)xv.z * wq.z + (double)xv.w * wq.w;
            }
#pragma unroll
            for (int off = 32; off; off >>= 1)
                acc += __shfl_xor(acc, off);
            if (lane == 0) redd[e] = acc;
        }
        __syncthreads();
        if (wv == 0) {
            double v = redd[lane];
            double m1 = v; int i1 = lane;
#pragma unroll
            for (int off = 32; off; off >>= 1) {
                double ov = __shfl_xor(m1, off); int oi = __shfl_xor(i1, off);
                if (ov > m1 || (ov == m1 && oi < i1)) { m1 = ov; i1 = oi; }
            }
            double m2 = (lane == i1) ? -INFINITY : v; int i2 = lane;
#pragma unroll
            for (int off = 32; off; off >>= 1) {
                double ov = __shfl_xor(m2, off); int oi = __shfl_xor(i2, off);
                if (ov > m2 || (ov == m2 && oi < i2)) { m2 = ov; i2 = oi; }
            }
            if (lane == 0) {
                double e2  = exp(m2 - m1);
                double inv = 1.0 / (1.0 + e2);
                out[2 * tok + 0] = (float)i1;
                out[2 * tok + 1] = (float)i2;
                out[2 * N_TOKENS + 2 * tok + 0] = (float)inv;
                out[2 * N_TOKENS + 2 * tok + 1] = (float)(e2 * inv);
            }
        }
        __syncthreads();
    }
}

// ---------------------------------------------------------------------------
extern "C" void kernel_launch(void* const* d_in, const int* in_sizes, int n_in,
                              void* d_out, int out_size, void* d_ws, size_t ws_size,
                              hipStream_t stream) {
    const float* x = (const float*)d_in[0];
    const float* W = (const float*)d_in[1];
    float* out = (float*)d_out;

    uint4* Bpack   = (uint4*)d_ws;                           // [0, 1MB)
    int*   flags   = (int*)((char*)d_ws + (1u << 20));       // [1MB, +64KB)
    float* partial = (float*)((char*)d_ws + (2u << 20));     // [2MB, 10MB)

    w_pack_bf16<<<128, 256, 0, stream>>>(W, Bpack, flags);
    router_gemm<<<(N_TOKENS / NT_BLK) * KS, 256, 0, stream>>>(x, Bpack, partial);
    finalize   <<<N_TOKENS / 4, 256, 0, stream>>>(partial, out, flags);
    refine     <<<128, 256, 0, stream>>>(x, W, flags, out);
}